// Round 1
// 599.456 us; speedup vs baseline: 1.0706x; 1.0706x over previous
//
#include <hip/hip_runtime.h>
#include <hip/hip_bf16.h>
#include <cstdint>

#define GLOBAL_AS __attribute__((address_space(1)))
#define LDS_AS    __attribute__((address_space(3)))

typedef __bf16 v8bf __attribute__((ext_vector_type(8)));
typedef __bf16 v4bf __attribute__((ext_vector_type(4)));
typedef float  v4f  __attribute__((ext_vector_type(4)));

struct P2 { __bf16* p[2]; };
struct P4 { __bf16* p[4]; };

#define BAR()   __builtin_amdgcn_s_barrier()
#define LGKM0() asm volatile("s_waitcnt lgkmcnt(0)" ::: "memory")
#define LGKM8() asm volatile("s_waitcnt lgkmcnt(8)" ::: "memory")
#define VMC6()  asm volatile("s_waitcnt vmcnt(6)" ::: "memory")

// --------- XCD-aware block remap, fully compile-time (flat%8 -> XCD) --------
template <int SWZ, int LBN, int LBM, int LNZ>
__device__ __forceinline__ void remap(int& bn, int& bm, int& bz) {
    if constexpr (!SWZ) {
        bn = blockIdx.x; bm = blockIdx.y; bz = blockIdx.z;
    } else {
        const unsigned f = blockIdx.x + (blockIdx.y << LBN) + (blockIdx.z << (LBN + LBM));
        const unsigned xcd = f & 7u, slot = f >> 3;
        constexpr unsigned T = (1u << (LNZ + LBM)) >> 3;   // (z,bm) pairs per XCD
        const unsigned p = xcd * T + (slot >> LBN);
        bn = (int)(slot & ((1u << LBN) - 1u));
        bm = (int)(p & ((1u << LBM) - 1u));
        bz = (int)(p >> LBM);
    }
}

// ---------------- 16-MFMA quadrant (one C-quadrant x K=64), T5 setprio ------
template <int IB, int JB>
__device__ __forceinline__ void mmq(v4f (&acc)[8][4], const v8bf (&As)[4][2],
                                    const v8bf (&Bs)[2][2]) {
    __builtin_amdgcn_s_setprio(1);
#pragma unroll
    for (int i = 0; i < 4; ++i)
#pragma unroll
        for (int j = 0; j < 2; ++j)
#pragma unroll
            for (int ks = 0; ks < 2; ++ks)
                acc[IB + i][JB + j] = __builtin_amdgcn_mfma_f32_16x16x32_bf16(
                    As[i][ks], Bs[j][ks], acc[IB + i][JB + j], 0, 0, 0);
    __builtin_amdgcn_s_setprio(0);
}

// ---------------- 256x256 tile, BK=64, 8-phase counted-vmcnt K-loop ---------
// LDS: 2 bufs x {A,B} x 2 half-regions of [128][64] bf16 (16 KiB each) = 128 KiB.
// A-half h holds global tile rows {s*128 + h*64 + rr : s in 0..1, rr in 0..63}
// B-half h holds global tile rows {s*64  + h*32 + rr : s in 0..3, rr in 0..31}
// so each half-region is ds_read in exactly ONE phase -> 1 half-stage/phase is
// overwrite-safe.  st_16x32 swizzle: LDS linear dest, inverse-swz global src,
// same XOR on read (involution; rule 21).
__device__ __forceinline__ void kloop256(
    const __bf16* __restrict__ A, int lda,
    const __bf16* __restrict__ B, int ldb, int K,
    __bf16* lds, v4f (&acc)[8][4], int tid)
{
    const int wave = tid >> 6, lane = tid & 63;
    const int quad = lane >> 4, l15 = lane & 15;
    const int wm = wave >> 2, wn = wave & 3;

    // ---- per-lane staging offsets (2 x global_load_lds of 16B per half) ----
    int ldsoff[2]; size_t offA[2], offB[2];
#pragma unroll
    for (int l = 0; l < 2; ++l) {
        const int rr = (l * 512 + tid) >> 3;                 // region row 0..127
        const int ce = ((tid & 7) * 8) ^ ((rr & 4) ? 16 : 0); // inverse swizzle
        offA[l] = (size_t)(((rr & ~63) << 1) + (rr & 63)) * lda + ce;
        offB[l] = (size_t)(((rr & ~31) << 1) + (rr & 31)) * ldb + ce;
        ldsoff[l] = (l * 512 + wave * 64) * 8;               // linear dest
    }
    const __bf16* Ah1 = A + (size_t)64 * lda;   // alpha1 row offset
    const __bf16* Bh1 = B + (size_t)32 * ldb;   // beta1 row offset

    auto stA = [&](const __bf16* G, int kt, __bf16* region) {
#pragma unroll
        for (int l = 0; l < 2; ++l)
            __builtin_amdgcn_global_load_lds(
                (const GLOBAL_AS void*)(G + offA[l] + kt),
                (LDS_AS void*)(region + ldsoff[l]), 16, 0, 0);
    };
    auto stB = [&](const __bf16* G, int kt, __bf16* region) {
#pragma unroll
        for (int l = 0; l < 2; ++l)
            __builtin_amdgcn_global_load_lds(
                (const GLOBAL_AS void*)(G + offB[l] + kt),
                (LDS_AS void*)(region + ldsoff[l]), 16, 0, 0);
    };

    // ---- per-lane read bases: swizzle XOR folds to a lane constant ----
    const int qsw = (quad << 4) ^ ((l15 & 4) ? 32 : 0);
    const int laneA = ((wm * 64 + l15) << 7) + qsw;
    const int laneB = ((wn * 32 + l15) << 7) + qsw;

    v8bf Aset[4][2], Ba[2][2], Bb[2][2];
    auto ldA = [&](const __bf16* region) {
        const char* p = (const char*)region + laneA;
#pragma unroll
        for (int i = 0; i < 4; ++i)
#pragma unroll
            for (int ks = 0; ks < 2; ++ks)
                Aset[i][ks] = *(const v8bf*)(p + i * 2048 + ks * 64);
    };
    auto ldB = [&](const __bf16* region, v8bf (&Bs)[2][2]) {
        const char* p = (const char*)region + laneB;
#pragma unroll
        for (int j = 0; j < 2; ++j)
#pragma unroll
            for (int ks = 0; ks < 2; ++ks)
                Bs[j][ks] = *(const v8bf*)(p + j * 2048 + ks * 64);
    };

    __bf16* const Ra0 = lds;              // buf0: tile u (even)
    __bf16* const Ra1 = lds + 8192;
    __bf16* const Rb0 = lds + 16384;
    __bf16* const Rb1 = lds + 24576;
    __bf16* const Sa0 = lds + 32768;      // buf1: tile u+1 (odd)
    __bf16* const Sa1 = lds + 40960;
    __bf16* const Sb0 = lds + 49152;
    __bf16* const Sb1 = lds + 57344;

    const int NT = K >> 6;
    const int kcap = K - 64;

    // prologue: t0 all 4 halves + t1 {a0,b0,b1}; wait t0 landed (14->6 loads)
    stA(A, 0, Ra0); stB(B, 0, Rb0); stB(Bh1, 0, Rb1); stA(Ah1, 0, Ra1);
    stA(A, 64, Sa0); stB(B, 64, Sb0); stB(Bh1, 64, Sb1);
    VMC6(); BAR();

    for (int it = 0; it < (NT >> 1); ++it) {
        const int u = it << 1;
        int ktA = (u + 2) << 6; if (ktA > kcap) ktA = kcap;  // clamp: tail stages
        int ktB = (u + 3) << 6; if (ktB > kcap) ktB = kcap;  // are garbage, unread
        const int kt1 = (u + 1) << 6;
        // ph0: Q(0,0) of tile u; stage (u+1).a1
        ldA(Ra0); ldB(Rb0, Ba);
        stA(Ah1, kt1, Sa1);
        LGKM8(); BAR(); LGKM0();
        mmq<0, 0>(acc, Aset, Ba);
        BAR();
        // ph1: Q(0,1); stage (u+2).a0 (Ra0 read done ph0)
        ldB(Rb1, Bb);
        stA(A, ktA, Ra0);
        BAR(); LGKM0();
        mmq<0, 2>(acc, Aset, Bb);
        BAR();
        // ph2: Q(1,1); stage (u+2).b0 (Rb0 read done ph0)
        ldA(Ra1);
        stB(B, ktA, Rb0);
        BAR(); LGKM0();
        mmq<4, 2>(acc, Aset, Bb);
        BAR();
        // ph3: Q(1,0); stage (u+2).b1 (Rb1 read done ph1); counted vmcnt
        stB(Bh1, ktA, Rb1);
        BAR(); LGKM0();
        mmq<4, 0>(acc, Aset, Ba);
        VMC6(); BAR();
        // ph4: Q(0,0) of tile u+1; stage (u+2).a1 (Ra1 read done ph2)
        ldA(Sa0); ldB(Sb0, Ba);
        stA(Ah1, ktA, Ra1);
        LGKM8(); BAR(); LGKM0();
        mmq<0, 0>(acc, Aset, Ba);
        BAR();
        // ph5: Q(0,1); stage (u+3).a0
        ldB(Sb1, Bb);
        stA(A, ktB, Sa0);
        BAR(); LGKM0();
        mmq<0, 2>(acc, Aset, Bb);
        BAR();
        // ph6: Q(1,1); stage (u+3).b0
        ldA(Sa1);
        stB(B, ktB, Sb0);
        BAR(); LGKM0();
        mmq<4, 2>(acc, Aset, Bb);
        BAR();
        // ph7: Q(1,0); stage (u+3).b1; counted vmcnt
        stB(Bh1, ktB, Sb1);
        BAR(); LGKM0();
        mmq<4, 0>(acc, Aset, Ba);
        VMC6(); BAR();
    }
}

// ---------------- generic GEMM: C = A * B^T (+col/row bias) ----------------
template <typename OutT, int SWZ, int LBN, int LBM, int LNZ>
__global__ __launch_bounds__(512, 2)
void gemm_bt(const __bf16* __restrict__ A, int lda, long long sA,
             const __bf16* __restrict__ B, int ldb, long long sB,
             OutT* __restrict__ C, int ldc, long long sC,
             int K,
             const float* __restrict__ bias_col,
             const float* __restrict__ bias_row)
{
    __shared__ __align__(16) __bf16 lds[2 * 4 * 8192];   // 128 KiB
    const int tid = threadIdx.x, wave = tid >> 6, lane = tid & 63;
    const int quad = lane >> 4, l15 = lane & 15;
    const int wm = wave >> 2, wn = wave & 3;
    int bn, bm, bz;
    remap<SWZ, LBN, LBM, LNZ>(bn, bm, bz);
    A += (long long)bz * sA;
    B += (long long)bz * sB;
    C += (long long)bz * sC;

    v4f acc[8][4];
#pragma unroll
    for (int i = 0; i < 8; ++i)
#pragma unroll
        for (int j = 0; j < 4; ++j) acc[i][j] = (v4f){0.f, 0.f, 0.f, 0.f};

    kloop256(A + (size_t)bm * 256 * lda, lda, B + (size_t)bn * 256 * ldb, ldb,
             K, lds, acc, tid);

#pragma unroll
    for (int i = 0; i < 8; ++i) {
        const int row0 = bm * 256 + wm * 128 + i * 16 + quad * 4;
#pragma unroll
        for (int j = 0; j < 4; ++j) {
            const int col = bn * 256 + wn * 64 + j * 16 + l15;
            const float bc = bias_col ? bias_col[col] : 0.f;
#pragma unroll
            for (int r = 0; r < 4; ++r) {
                float v = acc[i][j][r] + bc;
                if (bias_row) v += bias_row[row0 + r];
                C[(size_t)(row0 + r) * ldc + col] = (OutT)v;
            }
        }
    }
}

// ------------- scores GEMM with fused exp + row-sum atomics ----------------
template <int SWZ, int LBN, int LBM, int LNZ>
__global__ __launch_bounds__(512, 2)
void gemm_exp(const __bf16* __restrict__ A, int lda, long long sA,
              const __bf16* __restrict__ B, int ldb, long long sB,
              P2 Eout, int ldc,
              float* __restrict__ rowsum, int rsStride, int K)
{
    __shared__ __align__(16) __bf16 lds[2 * 4 * 8192];
    const int tid = threadIdx.x, wave = tid >> 6, lane = tid & 63;
    const int quad = lane >> 4, l15 = lane & 15;
    const int wm = wave >> 2, wn = wave & 3;
    int bn, bm, bz;
    remap<SWZ, LBN, LBM, LNZ>(bn, bm, bz);
    A += (long long)bz * sA;
    B += (long long)bz * sB;
    __bf16* C = Eout.p[bz];
    float* rs = rowsum + (long long)bz * rsStride;

    v4f acc[8][4];
#pragma unroll
    for (int i = 0; i < 8; ++i)
#pragma unroll
        for (int j = 0; j < 4; ++j) acc[i][j] = (v4f){0.f, 0.f, 0.f, 0.f};

    kloop256(A + (size_t)bm * 256 * lda, lda, B + (size_t)bn * 256 * ldb, ldb,
             K, lds, acc, tid);

#pragma unroll
    for (int i = 0; i < 8; ++i) {
        const int row0 = bm * 256 + wm * 128 + i * 16 + quad * 4;
        float part[4] = {0.f, 0.f, 0.f, 0.f};
#pragma unroll
        for (int j = 0; j < 4; ++j) {
            const int col = bn * 256 + wn * 64 + j * 16 + l15;
#pragma unroll
            for (int r = 0; r < 4; ++r) {
                float e = __expf(acc[i][j][r]);   // safe: |scaled score| << 88
                C[(size_t)(row0 + r) * ldc + col] = (__bf16)e;
                part[r] += e;
            }
        }
#pragma unroll
        for (int r = 0; r < 4; ++r) {
#pragma unroll
            for (int off = 1; off < 16; off <<= 1)
                part[r] += __shfl_xor(part[r], off, 16);
        }
        if (l15 == 0) {
#pragma unroll
            for (int r = 0; r < 4; ++r) atomicAdd(&rs[row0 + r], part[r]);
        }
    }
}

// ------------- ctx GEMM: C = diag(1/rowsum) * E * V  (per-z E pointers) ----
template <int SWZ, int LBN, int LBM, int LNZ>
__global__ __launch_bounds__(512, 2)
void gemm_av(P4 Ain, int lda,
             const __bf16* __restrict__ Bv, int ldb, long long sB,
             __bf16* __restrict__ C, int ldc, long long sC,
             const float* __restrict__ rowsum, int rsStride, int K)
{
    __shared__ __align__(16) __bf16 lds[2 * 4 * 8192];
    const int tid = threadIdx.x, wave = tid >> 6, lane = tid & 63;
    const int quad = lane >> 4, l15 = lane & 15;
    const int wm = wave >> 2, wn = wave & 3;
    int bn, bm, bz;
    remap<SWZ, LBN, LBM, LNZ>(bn, bm, bz);
    const __bf16* A = Ain.p[bz];
    const __bf16* B = Bv + (long long)bz * sB;
    C += (long long)bz * sC;
    const float* rs = rowsum + (long long)bz * rsStride;

    v4f acc[8][4];
#pragma unroll
    for (int i = 0; i < 8; ++i)
#pragma unroll
        for (int j = 0; j < 4; ++j) acc[i][j] = (v4f){0.f, 0.f, 0.f, 0.f};

    kloop256(A + (size_t)bm * 256 * lda, lda, B + (size_t)bn * 256 * ldb, ldb,
             K, lds, acc, tid);

#pragma unroll
    for (int i = 0; i < 8; ++i) {
        const int row0 = bm * 256 + wm * 128 + i * 16 + quad * 4;
        float inv[4];
#pragma unroll
        for (int r = 0; r < 4; ++r) inv[r] = 1.0f / rs[row0 + r];
#pragma unroll
        for (int j = 0; j < 4; ++j) {
            const int col = bn * 256 + wn * 64 + j * 16 + l15;
#pragma unroll
            for (int r = 0; r < 4; ++r)
                C[(size_t)(row0 + r) * ldc + col] = (__bf16)(acc[i][j][r] * inv[r]);
        }
    }
}

// ---------------- small helpers ----------------
__global__ void cvt_f32_bf16(const float* __restrict__ in, __bf16* __restrict__ out, int n4) {
    int i = blockIdx.x * blockDim.x + threadIdx.x;
    if (i >= n4) return;
    float4 f = ((const float4*)in)[i];
    v4bf o;
    o[0] = (__bf16)f.x; o[1] = (__bf16)f.y; o[2] = (__bf16)f.z; o[3] = (__bf16)f.w;
    ((v4bf*)out)[i] = o;
}

__global__ void cvt_w4(const float* __restrict__ w0, const float* __restrict__ w1,
                       const float* __restrict__ w2, const float* __restrict__ w3,
                       __bf16* __restrict__ dst, int n4, float wscale0) {
    const float* s = blockIdx.y == 0 ? w0 : blockIdx.y == 1 ? w1 : blockIdx.y == 2 ? w2 : w3;
    const float sc = blockIdx.y == 0 ? wscale0 : 1.f;
    int i = blockIdx.x * blockDim.x + threadIdx.x;
    if (i >= n4) return;
    float4 f = ((const float4*)s)[i];
    v4bf o;
    o[0] = (__bf16)(f.x * sc); o[1] = (__bf16)(f.y * sc);
    o[2] = (__bf16)(f.z * sc); o[3] = (__bf16)(f.w * sc);
    ((v4bf*)(dst + (size_t)blockIdx.y * n4 * 4))[i] = o;
}

__global__ void concat_bias2(const float* __restrict__ b0, const float* __restrict__ b1,
                             float* __restrict__ dst, int n, float s0) {
    int i = blockIdx.x * blockDim.x + threadIdx.x;
    if (i < n) dst[i] = b0[i] * s0;
    else if (i < 2 * n) dst[i] = b1[i - n];
}

__global__ void zero_f32(float* __restrict__ p, int n) {
    int i = blockIdx.x * blockDim.x + threadIdx.x;
    if (i < n) p[i] = 0.f;
}

extern "C" void kernel_launch(void* const* d_in, const int* in_sizes, int n_in,
                              void* d_out, int out_size, void* d_ws, size_t ws_size,
                              hipStream_t stream)
{
    const float* x  = (const float*)d_in[0];
    const float* Wq = (const float*)d_in[1];
    const float* bq = (const float*)d_in[2];
    const float* Wk = (const float*)d_in[3];
    const float* bk = (const float*)d_in[4];
    const float* Wv = (const float*)d_in[5];
    const float* bv = (const float*)d_in[6];
    const float* Wo = (const float*)d_in[7];
    const float* bo = (const float*)d_in[8];
    float* out = (float*)d_out;

    constexpr int B = 4, S = 4096, D = 1024;
    constexpr long long MS = (long long)B * S;
    constexpr float scale = 0.03125f;  // 1/sqrt(1024), exact pow2

    char* w = (char*)d_ws;
    size_t used = 0;
    auto alloc = [&](size_t bytes) -> char* {
        char* p = w + used;
        used += (bytes + 255) & ~(size_t)255;
        return p;
    };
    __bf16* xb  = (__bf16*)alloc((size_t)MS * D * 2);      // 32 MiB (later: ctx)
    __bf16* wqb = (__bf16*)alloc(4 * (size_t)D * D * 2);   // 8 MiB: sWq|Wk|Wv|Wo
    __bf16* wvb = wqb + 2 * (size_t)D * D;
    __bf16* wob = wqb + 3 * (size_t)D * D;
    float*  bqk = (float*)alloc(2 * D * 4);                // s*bq|bk
    float*  rsm = (float*)alloc((size_t)B * S * 4);        // 64 KiB row sums
    __bf16* qk  = (__bf16*)alloc((size_t)MS * 2 * D * 2);  // 64 MiB (front 32 MiB reused as E[b3])
    __bf16* vT  = (__bf16*)alloc((size_t)D * MS * 2);      // 32 MiB [1024][16384]
    __bf16* Efr = (__bf16*)alloc(3 * (size_t)S * S * 2);   // 96 MiB: E[b0..b2]
    __bf16* ctx = xb;  // xb dead after qk/vT projections
    if (used > ws_size) return;

    const long long SS = (long long)S * S;
    const long long qs = (long long)S * 2 * D;

    zero_f32<<<(B * S + 255) / 256, 256, 0, stream>>>(rsm, B * S);
    {
        int n4 = (int)(MS * D / 4);
        cvt_f32_bf16<<<(n4 + 255) / 256, 256, 0, stream>>>(x, xb, n4);
    }
    cvt_w4<<<dim3(D * D / 4 / 256, 4), 256, 0, stream>>>(Wq, Wk, Wv, Wo, wqb, D * D / 4, scale);
    concat_bias2<<<(2 * D + 255) / 256, 256, 0, stream>>>(bq, bk, bqk, D, scale);

    const dim3 blk(512);
    // qk = x [s*Wq | Wk]^T + [s*bq | bk]  [16384 x 2048]  grid (8,64,1) swizzled
    gemm_bt<__bf16, 1, 3, 6, 0><<<dim3(2 * D / 256, MS / 256), blk, 0, stream>>>(
        xb, D, 0, wqb, D, 0, qk, 2 * D, 0, D, bqk, nullptr);
    // vT[a][m] = Wv[a]·x[m] + bv[a]   [1024 x 16384]  grid (64,4) natural
    gemm_bt<__bf16, 0, 0, 0, 0><<<dim3(MS / 256, D / 256), blk, 0, stream>>>(
        wvb, D, 0, xb, D, 0, vT, (int)MS, 0, D, nullptr, bv);

    // E = exp(q k^T), pair-batched; rowsums via atomics.  grid (16,16,2) swizzled
    P2 e0; e0.p[0] = Efr;          e0.p[1] = Efr + SS;
    P2 e1; e1.p[0] = Efr + 2 * SS; e1.p[1] = qk;   // qk[b0,b1] rows dead after pair-0
    gemm_exp<1, 4, 4, 1><<<dim3(S / 256, S / 256, 2), blk, 0, stream>>>(
        qk, 2 * D, qs, qk + D, 2 * D, qs, e0, S, rsm, S, D);
    gemm_exp<1, 4, 4, 1><<<dim3(S / 256, S / 256, 2), blk, 0, stream>>>(
        qk + 2 * qs, 2 * D, qs, qk + D + 2 * qs, 2 * D, qs, e1, S, rsm + 2 * S, S, D);

    // ctx = diag(1/rowsum) E V, all 4 batches  grid (4,16,4) swizzled
    P4 ea; ea.p[0] = Efr; ea.p[1] = Efr + SS; ea.p[2] = Efr + 2 * SS; ea.p[3] = qk;
    gemm_av<1, 2, 4, 2><<<dim3(D / 256, S / 256, B), blk, 0, stream>>>(
        ea, S, vT, (int)MS, S, ctx, D, (long long)S * D, rsm, S, S);

    // out = ctx Wo^T + bo   grid (4,64,1) swizzled
    gemm_bt<float, 1, 2, 6, 0><<<dim3(D / 256, MS / 256), blk, 0, stream>>>(
        ctx, D, 0, wob, D, 0, out, D, 0, D, bo, nullptr);
}

// Round 2
// 556.513 us; speedup vs baseline: 1.1532x; 1.0772x over previous
//
#include <hip/hip_runtime.h>
#include <hip/hip_bf16.h>
#include <cstdint>

#define GLOBAL_AS __attribute__((address_space(1)))
#define LDS_AS    __attribute__((address_space(3)))

typedef __bf16 v8bf __attribute__((ext_vector_type(8)));
typedef __bf16 v4bf __attribute__((ext_vector_type(4)));
typedef float  v4f  __attribute__((ext_vector_type(4)));

struct P2 { __bf16* p[2]; };
struct P4 { __bf16* p[4]; };

#define BAR()   __builtin_amdgcn_s_barrier()
#define LGKM0() asm volatile("s_waitcnt lgkmcnt(0)" ::: "memory")
#define LGKM8() asm volatile("s_waitcnt lgkmcnt(8)" ::: "memory")
#define VMC6()  asm volatile("s_waitcnt vmcnt(6)" ::: "memory")

// --------- XCD-aware block remap, fully compile-time (flat%8 -> XCD) --------
template <int SWZ, int LBN, int LBM, int LNZ>
__device__ __forceinline__ void remap(int& bn, int& bm, int& bz) {
    if constexpr (!SWZ) {
        bn = blockIdx.x; bm = blockIdx.y; bz = blockIdx.z;
    } else {
        const unsigned f = blockIdx.x + (blockIdx.y << LBN) + (blockIdx.z << (LBN + LBM));
        const unsigned xcd = f & 7u, slot = f >> 3;
        constexpr unsigned T = (1u << (LNZ + LBM)) >> 3;   // (z,bm) pairs per XCD
        const unsigned p = xcd * T + (slot >> LBN);
        bn = (int)(slot & ((1u << LBN) - 1u));
        bm = (int)(p & ((1u << LBM) - 1u));
        bz = (int)(p >> LBM);
    }
}

// ---------------- 16-MFMA quadrant (one C-quadrant x K=64), T5 setprio ------
template <int IB, int JB>
__device__ __forceinline__ void mmq(v4f (&acc)[8][4], const v8bf (&As)[4][2],
                                    const v8bf (&Bs)[2][2]) {
    __builtin_amdgcn_s_setprio(1);
#pragma unroll
    for (int i = 0; i < 4; ++i)
#pragma unroll
        for (int j = 0; j < 2; ++j)
#pragma unroll
            for (int ks = 0; ks < 2; ++ks)
                acc[IB + i][JB + j] = __builtin_amdgcn_mfma_f32_16x16x32_bf16(
                    As[i][ks], Bs[j][ks], acc[IB + i][JB + j], 0, 0, 0);
    __builtin_amdgcn_s_setprio(0);
}

// ---------------- 256x256 tile, BK=64, 8-phase counted-vmcnt K-loop ---------
// LDS: 2 bufs x {A,B} x 2 half-regions of [128 rows][128 B] bf16 = 128 KiB.
// A-half h holds global tile rows {s*128 + h*64 + rr : s in 0..1, rr in 0..63}
// B-half h holds global tile rows {s*64  + h*32 + rr : s in 0..3, rr in 0..31}
// so each half-region is ds_read in exactly ONE phase -> 1 half-stage/phase is
// overwrite-safe.
// Swizzle (G4, 128-B rows): physical 16B slot = linear slot ^ (row&7).
// Applied as linear global_load_lds dest + inverse-permuted GLOBAL source +
// same XOR on ds_read (involution; rule 21).  row&7 == l15&7 on every read,
// so the XOR is a per-lane constant; ks half-select XORs bit 6 (two bases).
__device__ __forceinline__ void kloop256(
    const __bf16* __restrict__ A, int lda,
    const __bf16* __restrict__ B, int ldb, int K,
    __bf16* lds, v4f (&acc)[8][4], int tid)
{
    const int wave = tid >> 6, lane = tid & 63;
    const int quad = lane >> 4, l15 = lane & 15;
    const int wm = wave >> 2, wn = wave & 3;

    // ---- per-lane staging offsets (2 x global_load_lds of 16B per half) ----
    // physical chunk n = l*512+tid -> (row=n>>3, slot=n&7); its global source
    // is linear chunk slot^(row&7): element col = ((tid&7)^((tid>>3)&7))*8.
    const int ce = (((tid & 7) ^ ((tid >> 3) & 7)) << 3);
    int ldsoff[2]; size_t offA[2], offB[2];
#pragma unroll
    for (int l = 0; l < 2; ++l) {
        const int rr = (l * 512 + tid) >> 3;                 // region row 0..127
        offA[l] = (size_t)(((rr & ~63) << 1) + (rr & 63)) * lda + ce;
        offB[l] = (size_t)(((rr & ~31) << 1) + (rr & 31)) * ldb + ce;
        ldsoff[l] = (l * 512 + wave * 64) * 8;               // linear dest
    }
    const __bf16* Ah1 = A + (size_t)64 * lda;   // alpha1 row offset
    const __bf16* Bh1 = B + (size_t)32 * ldb;   // beta1 row offset

    auto stA = [&](const __bf16* G, int kt, __bf16* region) {
#pragma unroll
        for (int l = 0; l < 2; ++l)
            __builtin_amdgcn_global_load_lds(
                (const GLOBAL_AS void*)(G + offA[l] + kt),
                (LDS_AS void*)(region + ldsoff[l]), 16, 0, 0);
    };
    auto stB = [&](const __bf16* G, int kt, __bf16* region) {
#pragma unroll
        for (int l = 0; l < 2; ++l)
            __builtin_amdgcn_global_load_lds(
                (const GLOBAL_AS void*)(G + offB[l] + kt),
                (LDS_AS void*)(region + ldsoff[l]), 16, 0, 0);
    };

    // ---- per-lane read bases: 3-bit swizzle XOR folds to a lane constant ----
    const int qsw = (quad << 4) ^ ((l15 & 7) << 4);          // bits [6:4]
    const int laneA0 = ((wm * 64 + l15) << 7) + qsw;
    const int laneA1 = laneA0 ^ 64;                          // ks=1 half
    const int laneB0 = ((wn * 32 + l15) << 7) + qsw;
    const int laneB1 = laneB0 ^ 64;

    v8bf Aset[4][2], Ba[2][2], Bb[2][2];
    auto ldA = [&](const __bf16* region) {
        const char* p = (const char*)region;
#pragma unroll
        for (int i = 0; i < 4; ++i) {
            Aset[i][0] = *(const v8bf*)(p + laneA0 + i * 2048);
            Aset[i][1] = *(const v8bf*)(p + laneA1 + i * 2048);
        }
    };
    auto ldB = [&](const __bf16* region, v8bf (&Bs)[2][2]) {
        const char* p = (const char*)region;
#pragma unroll
        for (int j = 0; j < 2; ++j) {
            Bs[j][0] = *(const v8bf*)(p + laneB0 + j * 2048);
            Bs[j][1] = *(const v8bf*)(p + laneB1 + j * 2048);
        }
    };

    __bf16* const Ra0 = lds;              // buf0: tile u (even)
    __bf16* const Ra1 = lds + 8192;
    __bf16* const Rb0 = lds + 16384;
    __bf16* const Rb1 = lds + 24576;
    __bf16* const Sa0 = lds + 32768;      // buf1: tile u+1 (odd)
    __bf16* const Sa1 = lds + 40960;
    __bf16* const Sb0 = lds + 49152;
    __bf16* const Sb1 = lds + 57344;

    const int NT = K >> 6;
    const int kcap = K - 64;

    // prologue: t0 all 4 halves + t1 {a0,b0,b1}; wait t0 landed (14->6 loads)
    stA(A, 0, Ra0); stB(B, 0, Rb0); stB(Bh1, 0, Rb1); stA(Ah1, 0, Ra1);
    stA(A, 64, Sa0); stB(B, 64, Sb0); stB(Bh1, 64, Sb1);
    VMC6(); BAR();

    for (int it = 0; it < (NT >> 1); ++it) {
        const int u = it << 1;
        int ktA = (u + 2) << 6; if (ktA > kcap) ktA = kcap;  // clamp: tail stages
        int ktB = (u + 3) << 6; if (ktB > kcap) ktB = kcap;  // are garbage, unread
        const int kt1 = (u + 1) << 6;
        // ph0: Q(0,0) of tile u; stage (u+1).a1
        ldA(Ra0); ldB(Rb0, Ba);
        stA(Ah1, kt1, Sa1);
        LGKM8(); BAR(); LGKM0();
        mmq<0, 0>(acc, Aset, Ba);
        BAR();
        // ph1: Q(0,1); stage (u+2).a0 (Ra0 read done ph0)
        ldB(Rb1, Bb);
        stA(A, ktA, Ra0);
        BAR(); LGKM0();
        mmq<0, 2>(acc, Aset, Bb);
        BAR();
        // ph2: Q(1,1); stage (u+2).b0 (Rb0 read done ph0)
        ldA(Ra1);
        stB(B, ktA, Rb0);
        BAR(); LGKM0();
        mmq<4, 2>(acc, Aset, Bb);
        BAR();
        // ph3: Q(1,0); stage (u+2).b1 (Rb1 read done ph1); counted vmcnt
        stB(Bh1, ktA, Rb1);
        BAR(); LGKM0();
        mmq<4, 0>(acc, Aset, Ba);
        VMC6(); BAR();
        // ph4: Q(0,0) of tile u+1; stage (u+2).a1 (Ra1 read done ph2)
        ldA(Sa0); ldB(Sb0, Ba);
        stA(Ah1, ktA, Ra1);
        LGKM8(); BAR(); LGKM0();
        mmq<0, 0>(acc, Aset, Ba);
        BAR();
        // ph5: Q(0,1); stage (u+3).a0
        ldB(Sb1, Bb);
        stA(A, ktB, Sa0);
        BAR(); LGKM0();
        mmq<0, 2>(acc, Aset, Bb);
        BAR();
        // ph6: Q(1,1); stage (u+3).b0
        ldA(Sa1);
        stB(B, ktB, Sb0);
        BAR(); LGKM0();
        mmq<4, 2>(acc, Aset, Bb);
        BAR();
        // ph7: Q(1,0); stage (u+3).b1; counted vmcnt
        stB(Bh1, ktB, Sb1);
        BAR(); LGKM0();
        mmq<4, 0>(acc, Aset, Ba);
        VMC6(); BAR();
    }
}

// ---------------- generic GEMM: C = A * B^T (+col/row bias) ----------------
template <typename OutT, int SWZ, int LBN, int LBM, int LNZ>
__global__ __launch_bounds__(512, 2)
void gemm_bt(const __bf16* __restrict__ A, int lda, long long sA,
             const __bf16* __restrict__ B, int ldb, long long sB,
             OutT* __restrict__ C, int ldc, long long sC,
             int K,
             const float* __restrict__ bias_col,
             const float* __restrict__ bias_row)
{
    __shared__ __align__(16) __bf16 lds[2 * 4 * 8192];   // 128 KiB
    const int tid = threadIdx.x, wave = tid >> 6, lane = tid & 63;
    const int quad = lane >> 4, l15 = lane & 15;
    const int wm = wave >> 2, wn = wave & 3;
    int bn, bm, bz;
    remap<SWZ, LBN, LBM, LNZ>(bn, bm, bz);
    A += (long long)bz * sA;
    B += (long long)bz * sB;
    C += (long long)bz * sC;

    v4f acc[8][4];
#pragma unroll
    for (int i = 0; i < 8; ++i)
#pragma unroll
        for (int j = 0; j < 4; ++j) acc[i][j] = (v4f){0.f, 0.f, 0.f, 0.f};

    kloop256(A + (size_t)bm * 256 * lda, lda, B + (size_t)bn * 256 * ldb, ldb,
             K, lds, acc, tid);

#pragma unroll
    for (int i = 0; i < 8; ++i) {
        const int row0 = bm * 256 + wm * 128 + i * 16 + quad * 4;
#pragma unroll
        for (int j = 0; j < 4; ++j) {
            const int col = bn * 256 + wn * 64 + j * 16 + l15;
            const float bc = bias_col ? bias_col[col] : 0.f;
#pragma unroll
            for (int r = 0; r < 4; ++r) {
                float v = acc[i][j][r] + bc;
                if (bias_row) v += bias_row[row0 + r];
                C[(size_t)(row0 + r) * ldc + col] = (OutT)v;
            }
        }
    }
}

// ------------- scores GEMM with fused exp + row-sum atomics ----------------
template <int SWZ, int LBN, int LBM, int LNZ>
__global__ __launch_bounds__(512, 2)
void gemm_exp(const __bf16* __restrict__ A, int lda, long long sA,
              const __bf16* __restrict__ B, int ldb, long long sB,
              P2 Eout, int ldc,
              float* __restrict__ rowsum, int rsStride, int K)
{
    __shared__ __align__(16) __bf16 lds[2 * 4 * 8192];
    const int tid = threadIdx.x, wave = tid >> 6, lane = tid & 63;
    const int quad = lane >> 4, l15 = lane & 15;
    const int wm = wave >> 2, wn = wave & 3;
    int bn, bm, bz;
    remap<SWZ, LBN, LBM, LNZ>(bn, bm, bz);
    A += (long long)bz * sA;
    B += (long long)bz * sB;
    __bf16* C = Eout.p[bz];
    float* rs = rowsum + (long long)bz * rsStride;

    v4f acc[8][4];
#pragma unroll
    for (int i = 0; i < 8; ++i)
#pragma unroll
        for (int j = 0; j < 4; ++j) acc[i][j] = (v4f){0.f, 0.f, 0.f, 0.f};

    kloop256(A + (size_t)bm * 256 * lda, lda, B + (size_t)bn * 256 * ldb, ldb,
             K, lds, acc, tid);

#pragma unroll
    for (int i = 0; i < 8; ++i) {
        const int row0 = bm * 256 + wm * 128 + i * 16 + quad * 4;
        float part[4] = {0.f, 0.f, 0.f, 0.f};
#pragma unroll
        for (int j = 0; j < 4; ++j) {
            const int col = bn * 256 + wn * 64 + j * 16 + l15;
#pragma unroll
            for (int r = 0; r < 4; ++r) {
                float e = __expf(acc[i][j][r]);   // safe: |scaled score| << 88
                C[(size_t)(row0 + r) * ldc + col] = (__bf16)e;
                part[r] += e;
            }
        }
#pragma unroll
        for (int r = 0; r < 4; ++r) {
#pragma unroll
            for (int off = 1; off < 16; off <<= 1)
                part[r] += __shfl_xor(part[r], off, 16);
        }
        if (l15 == 0) {
#pragma unroll
            for (int r = 0; r < 4; ++r) atomicAdd(&rs[row0 + r], part[r]);
        }
    }
}

// ------------- ctx GEMM: C = diag(1/rowsum) * E * V  (per-z E pointers) ----
template <int SWZ, int LBN, int LBM, int LNZ>
__global__ __launch_bounds__(512, 2)
void gemm_av(P4 Ain, int lda,
             const __bf16* __restrict__ Bv, int ldb, long long sB,
             __bf16* __restrict__ C, int ldc, long long sC,
             const float* __restrict__ rowsum, int rsStride, int K)
{
    __shared__ __align__(16) __bf16 lds[2 * 4 * 8192];
    const int tid = threadIdx.x, wave = tid >> 6, lane = tid & 63;
    const int quad = lane >> 4, l15 = lane & 15;
    const int wm = wave >> 2, wn = wave & 3;
    int bn, bm, bz;
    remap<SWZ, LBN, LBM, LNZ>(bn, bm, bz);
    const __bf16* A = Ain.p[bz];
    const __bf16* B = Bv + (long long)bz * sB;
    C += (long long)bz * sC;
    const float* rs = rowsum + (long long)bz * rsStride;

    v4f acc[8][4];
#pragma unroll
    for (int i = 0; i < 8; ++i)
#pragma unroll
        for (int j = 0; j < 4; ++j) acc[i][j] = (v4f){0.f, 0.f, 0.f, 0.f};

    kloop256(A + (size_t)bm * 256 * lda, lda, B + (size_t)bn * 256 * ldb, ldb,
             K, lds, acc, tid);

#pragma unroll
    for (int i = 0; i < 8; ++i) {
        const int row0 = bm * 256 + wm * 128 + i * 16 + quad * 4;
        float inv[4];
#pragma unroll
        for (int r = 0; r < 4; ++r) inv[r] = 1.0f / rs[row0 + r];
#pragma unroll
        for (int j = 0; j < 4; ++j) {
            const int col = bn * 256 + wn * 64 + j * 16 + l15;
#pragma unroll
            for (int r = 0; r < 4; ++r)
                C[(size_t)(row0 + r) * ldc + col] = (__bf16)(acc[i][j][r] * inv[r]);
        }
    }
}

// ---------------- small helpers ----------------
__global__ void cvt_f32_bf16(const float* __restrict__ in, __bf16* __restrict__ out, int n4) {
    int i = blockIdx.x * blockDim.x + threadIdx.x;
    if (i >= n4) return;
    float4 f = ((const float4*)in)[i];
    v4bf o;
    o[0] = (__bf16)f.x; o[1] = (__bf16)f.y; o[2] = (__bf16)f.z; o[3] = (__bf16)f.w;
    ((v4bf*)out)[i] = o;
}

__global__ void cvt_w4(const float* __restrict__ w0, const float* __restrict__ w1,
                       const float* __restrict__ w2, const float* __restrict__ w3,
                       __bf16* __restrict__ dst, int n4, float wscale0) {
    const float* s = blockIdx.y == 0 ? w0 : blockIdx.y == 1 ? w1 : blockIdx.y == 2 ? w2 : w3;
    const float sc = blockIdx.y == 0 ? wscale0 : 1.f;
    int i = blockIdx.x * blockDim.x + threadIdx.x;
    if (i >= n4) return;
    float4 f = ((const float4*)s)[i];
    v4bf o;
    o[0] = (__bf16)(f.x * sc); o[1] = (__bf16)(f.y * sc);
    o[2] = (__bf16)(f.z * sc); o[3] = (__bf16)(f.w * sc);
    ((v4bf*)(dst + (size_t)blockIdx.y * n4 * 4))[i] = o;
}

__global__ void concat_bias2(const float* __restrict__ b0, const float* __restrict__ b1,
                             float* __restrict__ dst, int n, float s0) {
    int i = blockIdx.x * blockDim.x + threadIdx.x;
    if (i < n) dst[i] = b0[i] * s0;
    else if (i < 2 * n) dst[i] = b1[i - n];
}

__global__ void zero_f32(float* __restrict__ p, int n) {
    int i = blockIdx.x * blockDim.x + threadIdx.x;
    if (i < n) p[i] = 0.f;
}

extern "C" void kernel_launch(void* const* d_in, const int* in_sizes, int n_in,
                              void* d_out, int out_size, void* d_ws, size_t ws_size,
                              hipStream_t stream)
{
    const float* x  = (const float*)d_in[0];
    const float* Wq = (const float*)d_in[1];
    const float* bq = (const float*)d_in[2];
    const float* Wk = (const float*)d_in[3];
    const float* bk = (const float*)d_in[4];
    const float* Wv = (const float*)d_in[5];
    const float* bv = (const float*)d_in[6];
    const float* Wo = (const float*)d_in[7];
    const float* bo = (const float*)d_in[8];
    float* out = (float*)d_out;

    constexpr int B = 4, S = 4096, D = 1024;
    constexpr long long MS = (long long)B * S;
    constexpr float scale = 0.03125f;  // 1/sqrt(1024), exact pow2

    char* w = (char*)d_ws;
    size_t used = 0;
    auto alloc = [&](size_t bytes) -> char* {
        char* p = w + used;
        used += (bytes + 255) & ~(size_t)255;
        return p;
    };
    __bf16* xb  = (__bf16*)alloc((size_t)MS * D * 2);      // 32 MiB (later: ctx)
    __bf16* wqb = (__bf16*)alloc(4 * (size_t)D * D * 2);   // 8 MiB: sWq|Wk|Wv|Wo
    __bf16* wvb = wqb + 2 * (size_t)D * D;
    __bf16* wob = wqb + 3 * (size_t)D * D;
    float*  bqk = (float*)alloc(2 * D * 4);                // s*bq|bk
    float*  rsm = (float*)alloc((size_t)B * S * 4);        // 64 KiB row sums
    __bf16* qk  = (__bf16*)alloc((size_t)MS * 2 * D * 2);  // 64 MiB (front 32 MiB reused as E[b3])
    __bf16* vT  = (__bf16*)alloc((size_t)D * MS * 2);      // 32 MiB [1024][16384]
    __bf16* Efr = (__bf16*)alloc(3 * (size_t)S * S * 2);   // 96 MiB: E[b0..b2]
    __bf16* ctx = xb;  // xb dead after qk/vT projections
    if (used > ws_size) return;

    const long long SS = (long long)S * S;
    const long long qs = (long long)S * 2 * D;

    zero_f32<<<(B * S + 255) / 256, 256, 0, stream>>>(rsm, B * S);
    {
        int n4 = (int)(MS * D / 4);
        cvt_f32_bf16<<<(n4 + 255) / 256, 256, 0, stream>>>(x, xb, n4);
    }
    cvt_w4<<<dim3(D * D / 4 / 256, 4), 256, 0, stream>>>(Wq, Wk, Wv, Wo, wqb, D * D / 4, scale);
    concat_bias2<<<(2 * D + 255) / 256, 256, 0, stream>>>(bq, bk, bqk, D, scale);

    const dim3 blk(512);
    // qk = x [s*Wq | Wk]^T + [s*bq | bk]  [16384 x 2048]  grid (8,64,1) swizzled
    gemm_bt<__bf16, 1, 3, 6, 0><<<dim3(2 * D / 256, MS / 256), blk, 0, stream>>>(
        xb, D, 0, wqb, D, 0, qk, 2 * D, 0, D, bqk, nullptr);
    // vT[a][m] = Wv[a]·x[m] + bv[a]   [1024 x 16384]  grid (64,4) natural
    gemm_bt<__bf16, 0, 0, 0, 0><<<dim3(MS / 256, D / 256), blk, 0, stream>>>(
        wvb, D, 0, xb, D, 0, vT, (int)MS, 0, D, nullptr, bv);

    // E = exp(q k^T), pair-batched; rowsums via atomics.  grid (16,16,2) swizzled
    P2 e0; e0.p[0] = Efr;          e0.p[1] = Efr + SS;
    P2 e1; e1.p[0] = Efr + 2 * SS; e1.p[1] = qk;   // qk[b0,b1] rows dead after pair-0
    gemm_exp<1, 4, 4, 1><<<dim3(S / 256, S / 256, 2), blk, 0, stream>>>(
        qk, 2 * D, qs, qk + D, 2 * D, qs, e0, S, rsm, S, D);
    gemm_exp<1, 4, 4, 1><<<dim3(S / 256, S / 256, 2), blk, 0, stream>>>(
        qk + 2 * qs, 2 * D, qs, qk + D + 2 * qs, 2 * D, qs, e1, S, rsm + 2 * S, S, D);

    // ctx = diag(1/rowsum) E V, all 4 batches  grid (4,16,4) swizzled
    P4 ea; ea.p[0] = Efr; ea.p[1] = Efr + SS; ea.p[2] = Efr + 2 * SS; ea.p[3] = qk;
    gemm_av<1, 2, 4, 2><<<dim3(D / 256, S / 256, B), blk, 0, stream>>>(
        ea, S, vT, (int)MS, S, ctx, D, (long long)S * D, rsm, S, S);

    // out = ctx Wo^T + bo   grid (4,64,1) swizzled
    gemm_bt<float, 1, 2, 6, 0><<<dim3(D / 256, MS / 256), blk, 0, stream>>>(
        ctx, D, 0, wob, D, 0, out, D, 0, D, bo, nullptr);
}